// Round 6
// baseline (281.945 us; speedup 1.0000x reference)
//
#include <hip/hip_runtime.h>
#include <stdint.h>

typedef unsigned short u16;
typedef unsigned int u32;
typedef u16   u16x4  __attribute__((ext_vector_type(4)));
typedef u16   u16x8  __attribute__((ext_vector_type(8)));
typedef __bf16 bf16x8 __attribute__((ext_vector_type(8)));
typedef float f32x4  __attribute__((ext_vector_type(4)));
typedef u32   u32x2  __attribute__((ext_vector_type(2)));
typedef u32   u32x4  __attribute__((ext_vector_type(4)));

typedef __attribute__((address_space(3))) u16 lds_u16;
typedef __attribute__((address_space(1))) const u16 glb_u16;

static __device__ __forceinline__ u16 f32_bf16(float f) {
    uint32_t u = __builtin_bit_cast(uint32_t, f);
    u += 0x7fffu + ((u >> 16) & 1u);          // round-to-nearest-even
    return (u16)(u >> 16);
}
// fast pair-pack: round-half-up + byte-perm (ties-only diff vs RNE)
static __device__ __forceinline__ u32 pack2(float a, float b) {
#if __has_builtin(__builtin_amdgcn_perm)
    u32 ua = __builtin_bit_cast(u32, a) + 0x8000u;
    u32 ub = __builtin_bit_cast(u32, b) + 0x8000u;
    return __builtin_amdgcn_perm(ub, ua, 0x07060302u);   // {ua.hi, ub.hi}
#else
    return (u32)f32_bf16(a) | ((u32)f32_bf16(b) << 16);
#endif
}
#if __has_builtin(__builtin_amdgcn_exp2f)
#define EXP2(x) __builtin_amdgcn_exp2f(x)
#else
#define EXP2(x) __expf((x) * 0.69314718056f)
#endif
static __device__ __forceinline__ u16x8 cvt8(f32x4 a, f32x4 b) {
    u16x8 v;
#pragma unroll
    for (int e = 0; e < 4; ++e) { v[e] = f32_bf16(a[e]); v[4 + e] = f32_bf16(b[e]); }
    return v;
}

// inline dtype-flag (verified R5-R13 semantics): count exps >= 0xC2 in the
// first 1024 u16 of X; >32 -> fp32 inputs AND fp32 output. Deterministic and
// identical in every block -> safe to compute per-block (no detect dispatch).
static __device__ __forceinline__ bool flag_reduce(const u16* __restrict__ X0,
                                                   int* cnt /*>=256 ints LDS*/) {
    const int t = threadIdx.x;
    int c = 0;
#pragma unroll
    for (int i = 0; i < 4; ++i) {
        u16 v = X0[t + 256 * i];
        int e = (v >> 7) & 0xFF;
        c += (e >= 0xC2) ? 1 : 0;
    }
    cnt[t] = c;
    __syncthreads();
    for (int s = 128; s > 0; s >>= 1) {
        if (t < s) cnt[t] += cnt[t + s];
        __syncthreads();
    }
    bool f = cnt[0] > 32;
    __syncthreads();
    return f;
}

// ---------------------------------------------------------------------------
// 0. Merged convert: grid (256, 10). y<2 -> X jobs (bf16 convert / copy),
//    y>=2 -> weight convert+transpose job y-2. Flag computed inline.
// ---------------------------------------------------------------------------
struct XJob { const void* in; u16* out; int n; };
struct WJob { const void* in; u16* out; };
struct WBatch8 { WJob j[8]; };

__global__ __launch_bounds__(256) void convert_all(XJob j0, XJob j1, WBatch8 args) {
    __shared__ int cnt[256];
    __shared__ u16 tile[64][72];
    const bool f32in = flag_reduce((const u16*)j0.in, cnt);
    const int t = threadIdx.x;

    if (blockIdx.y < 2) {
        const XJob job = (blockIdx.y == 0) ? j0 : j1;
        const int stride = gridDim.x * 256 * 8;
        for (int i = ((int)blockIdx.x * 256 + t) * 8; i < job.n; i += stride) {
            u16x8 v;
            if (f32in) {
                const float* p = (const float*)job.in + i;
                v = cvt8(*(const f32x4*)p, *(const f32x4*)(p + 4));
            } else {
                v = *(const u16x8*)((const u16*)job.in + i);
            }
            *(u16x8*)(job.out + i) = v;
        }
        return;
    }

    const int wj = blockIdx.y - 2;
    const void* in = args.j[wj].in;
    u16*       out = args.j[wj].out;
    const int r0 = ((int)blockIdx.x >> 4) * 64, c0 = ((int)blockIdx.x & 15) * 64;
    const int lr = t >> 3, lc = (t & 7) * 8;
#pragma unroll
    for (int pass = 0; pass < 2; ++pass) {
        int r = lr + pass * 32;
        u16x8 v;
        if (f32in) {
            const float* p = (const float*)in + (size_t)(r0 + r) * 1024 + c0 + lc;
            v = cvt8(*(const f32x4*)p, *(const f32x4*)(p + 4));
        } else {
            v = *(const u16x8*)((const u16*)in + (size_t)(r0 + r) * 1024 + c0 + lc);
        }
#pragma unroll
        for (int e = 0; e < 8; ++e) tile[r][lc + e] = v[e];
    }
    __syncthreads();
#pragma unroll
    for (int pass = 0; pass < 2; ++pass) {
        int n = lr + pass * 32;
        u16x8 v;
#pragma unroll
        for (int e = 0; e < 8; ++e) v[e] = tile[lc + e][n];
        *(u16x8*)(out + (size_t)(c0 + n) * 1024 + r0 + lc) = v;
    }
}

// ---------------------------------------------------------------------------
// 2. MFMA GEMM, BK=64, global_load_lds staging. Flat 1-D grid, LPT order,
//    bid%8 == m-tile%8 preserved (XCD L2 locality). mode=1: pre-GEMM
//    (jobs 3,4,5 [M=3072] first, then 0,1,2 [M=2048]; 960 blocks).
//    mode=2: final GEMM with SPLIT-K x2 (640 blocks; adjacent bids = same
//    tile, different k-half -> L2 panel sharing). fp32-out path (flag=1)
//    accumulates via atomicAdd into pre-zeroed d_out; bf16 path (flag=0)
//    unchanged: kh=1 blocks exit, kh=0 blocks run full K.
// ---------------------------------------------------------------------------
struct GemmJob  { const u16* A; const u16* Bt; void* C; int M; int cF32able; int cOffElems; int vtNk; float cScale; };
struct GemmBatch6 { GemmJob j[6]; const u16* flagSrc; int mode; };

__global__ __launch_bounds__(256) void gemm_bt(GemmBatch6 b) {
    const int K = 1024, N = 1024;
    int jz, m_t, n_t, kh = 0;
    {
        int bid = blockIdx.x;
        if (b.mode == 1) {
            if (bid < 576) { jz = 3 + bid / 192; int r = bid % 192; m_t = r % 24; n_t = r / 24; }
            else { int b2 = bid - 576; jz = b2 / 128; int r = b2 % 128; m_t = r % 16; n_t = r / 16; }
        } else {
            // 640 blocks: job0 = 192 tiles x2 khalf, job1 = 128 tiles x2 khalf
            if (bid < 384) { jz = 0; int tl = bid >> 1; kh = bid & 1; m_t = tl % 24; n_t = tl / 24; }
            else { int b2 = bid - 384; jz = 1; int tl = b2 >> 1; kh = b2 & 1; m_t = tl % 16; n_t = tl / 16; }
        }
    }
    const GemmJob job = b.j[jz];
    const int m0 = m_t * 128, n0 = n_t * 128;
    if (m0 >= job.M) return;

    __shared__ u16 As[128 * 64];
    __shared__ u16 Bs[128 * 64];

    bool cF = false;
    if (b.mode == 2 && job.cF32able) {
        cF = flag_reduce(b.flagSrc, (int*)As);   // As reused pre-staging
    }
    // bf16-out path keeps the old single-block-per-tile schedule
    if (b.mode == 2 && !cF && kh) return;
    int k0beg = 0, k0end = K;
    if (b.mode == 2 && cF) { k0beg = kh * 512; k0end = k0beg + 512; }

    const int tid  = threadIdx.x;
    const int lane = tid & 63, wave = tid >> 6;
    const int quad = lane >> 4, l16 = lane & 15;
    const int wrow = wave >> 1, wcol = wave & 1;

    f32x4 acc[4][4];
#pragma unroll
    for (int i = 0; i < 4; ++i)
#pragma unroll
        for (int j = 0; j < 4; ++j) acc[i][j] = (f32x4){0.f, 0.f, 0.f, 0.f};

    for (int k0 = k0beg; k0 < k0end; k0 += 64) {
        __syncthreads();
#pragma unroll
        for (int i = 0; i < 4; ++i) {
            int id = tid + 256 * i;
            int row = id >> 3, slot = id & 7;
            int src = (slot ^ (row & 7)) * 8;
            __builtin_amdgcn_global_load_lds(
                (glb_u16*)(job.A + (size_t)(m0 + row) * K + k0 + src),
                (lds_u16*)(As + (size_t)id * 8), 16, 0, 0);
            __builtin_amdgcn_global_load_lds(
                (glb_u16*)(job.Bt + (size_t)(n0 + row) * K + k0 + src),
                (lds_u16*)(Bs + (size_t)id * 8), 16, 0, 0);
        }
        __syncthreads();

#pragma unroll
        for (int kc2 = 0; kc2 < 2; ++kc2) {
            bf16x8 af[4], bfb[4];
#pragma unroll
            for (int i = 0; i < 4; ++i) {
                int r  = wrow * 64 + i * 16 + l16;
                af[i]  = *(const bf16x8*)(As + r * 64 + (((kc2 * 4 + quad) ^ (r & 7)) * 8));
                int rn = wcol * 64 + i * 16 + l16;
                bfb[i] = *(const bf16x8*)(Bs + rn * 64 + (((kc2 * 4 + quad) ^ (rn & 7)) * 8));
            }
#pragma unroll
            for (int i = 0; i < 4; ++i)
#pragma unroll
                for (int j = 0; j < 4; ++j)
                    acc[i][j] = __builtin_amdgcn_mfma_f32_16x16x32_bf16(af[i], bfb[j], acc[i][j], 0, 0, 0);
        }
    }

    if (job.vtNk > 0) {
        u16* VT = (u16*)job.C;
        const int Nk2 = job.vtNk;
#pragma unroll
        for (int i = 0; i < 4; ++i)
#pragma unroll
            for (int j = 0; j < 4; ++j) {
                int n   = n0 + wcol * 64 + j * 16 + l16;
                int hh  = n >> 6, dd = n & 63;
                int key = m0 + wrow * 64 + i * 16 + quad * 4;
                int bq  = key & 31;
                int kp  = (key & ~31) | (((bq >> 2) & 3) * 8 + (bq >> 4) * 4);  // permuted
                u16x4 vv;
#pragma unroll
                for (int r = 0; r < 4; ++r) vv[r] = f32_bf16(acc[i][j][r]);
                *(u16x4*)(VT + (size_t)hh * 64 * Nk2 + (size_t)dd * Nk2 + kp) = vv;
            }
    } else if (cF) {
        float* C = (float*)job.C + job.cOffElems;
#pragma unroll
        for (int i = 0; i < 4; ++i)
#pragma unroll
            for (int j = 0; j < 4; ++j)
#pragma unroll
                for (int r = 0; r < 4; ++r) {
                    int gr = m0 + wrow * 64 + i * 16 + quad * 4 + r;
                    int gc = n0 + wcol * 64 + j * 16 + l16;
                    atomicAdd(&C[(size_t)gr * N + gc], acc[i][j][r]);   // split-K combine
                }
    } else {
        u16* C = (u16*)job.C + job.cOffElems;
        const float cs = job.cScale;
#pragma unroll
        for (int i = 0; i < 4; ++i)
#pragma unroll
            for (int j = 0; j < 4; ++j)
#pragma unroll
                for (int r = 0; r < 4; ++r) {
                    int gr = m0 + wrow * 64 + i * 16 + quad * 4 + r;
                    int gc = n0 + wcol * 64 + j * 16 + l16;
                    C[(size_t)gr * N + gc] = f32_bf16(acc[i][j][r] * cs);
                }
    }
}

// ---------------------------------------------------------------------------
// 3. Fused MFMA attention v10 + T5 setprio around MFMA clusters (m191: +4-7%
//    when resident blocks are phase-diverse; 8 independent blocks/CU here).
//    Structure unchanged: 4 waves x 16 q-rows, shared double-buffered K/V
//    tiles, issue-early DMA, one barrier per iter.
// ---------------------------------------------------------------------------
struct AttnDir { const u16* Q; const u16* K; const u16* VT; u16* ctxT; int Nq; int Nk; int nBlk; };

__global__ __launch_bounds__(256, 8) void attn_k(AttnDir d0, AttnDir d1) {
    const int D = 1024;
    int b = blockIdx.x;
    const AttnDir dd = (b < d0.nBlk) ? d0 : d1;
    if (blockIdx.x >= (unsigned)d0.nBlk) b -= d0.nBlk;
    const int h  = b & 15;
    const int q0 = (b >> 4) * 64;
    const int Nq = dd.Nq, Nk = dd.Nk;
    const u16* __restrict__ Qp  = dd.Q;
    const u16* __restrict__ Kp  = dd.K;
    const u16* __restrict__ VTp = dd.VT;

    const int tid  = threadIdx.x;
    const int lane = tid & 63, w = tid >> 6;
    const int quad = lane >> 4, l16 = lane & 15;

    __shared__ u16 smem[2][4096];     // [buf][K 2048 u16 | V 2048 u16] = 16 KB

    // Q fragments (B operands), pre-scaled by QSC at GEMM time
    bf16x8 aq[2];
#pragma unroll
    for (int kc = 0; kc < 2; ++kc) {
        int q = q0 + w * 16 + l16;
        aq[kc] = *(const bf16x8*)(Qp + (size_t)q * D + h * 64 + kc * 32 + quad * 8);
    }

    f32x4 o[4];                       // O^T accumulators [nj]
#pragma unroll
    for (int nj = 0; nj < 4; ++nj) o[nj] = (f32x4){0.f, 0.f, 0.f, 0.f};
    float rs = 0.f;                   // per-lane partial row-sum (q = l16)

    // staging sources: each thread DMAs one 16B K chunk + one 16B V chunk
    const int krow = tid >> 3;
    const int ksrc = ((tid & 7) ^ (krow & 7)) * 8;      // pre-swizzled global src
    const u16* kg = Kp + (size_t)krow * D + h * 64 + ksrc;
    const u16* vg = VTp + (size_t)h * 64 * Nk + (size_t)(tid >> 2) * Nk + (tid & 3) * 8;

    const int nt = Nk >> 5;
    // prologue: stage tile 0 -> buf 0
    __builtin_amdgcn_global_load_lds((glb_u16*)kg, (lds_u16*)(&smem[0][0] + tid * 8), 16, 0, 0);
    __builtin_amdgcn_global_load_lds((glb_u16*)vg, (lds_u16*)(&smem[0][2048] + tid * 8), 16, 0, 0);
    kg += (size_t)32 * D; vg += 32;
    __syncthreads();

    for (int t = 0; t < nt; ++t) {
        const u16* Ks = &smem[t & 1][0];
        const u16* Vs = Ks + 2048;
        if (t + 1 < nt) {             // issue next-tile DMA BEFORE compute
            u16* dst = &smem[(t + 1) & 1][0];
            __builtin_amdgcn_global_load_lds((glb_u16*)kg, (lds_u16*)(dst + tid * 8), 16, 0, 0);
            __builtin_amdgcn_global_load_lds((glb_u16*)vg, (lds_u16*)(dst + 2048 + tid * 8), 16, 0, 0);
            kg += (size_t)32 * D; vg += 32;
        }

        // S^T = K Q^T   (A = K fragment, B = Q fragment)
        f32x4 s[2];
#pragma unroll
        for (int kn = 0; kn < 2; ++kn) s[kn] = (f32x4){0.f, 0.f, 0.f, 0.f};
        __builtin_amdgcn_s_setprio(1);
#pragma unroll
        for (int kn = 0; kn < 2; ++kn)
#pragma unroll
            for (int kc = 0; kc < 2; ++kc) {
                int keyr = kn * 16 + l16;
                int phys = ((kc * 4 + quad) ^ (keyr & 7)) * 8;
                bf16x8 ak = *(const bf16x8*)(Ks + keyr * 64 + phys);
                s[kn] = __builtin_amdgcn_mfma_f32_16x16x32_bf16(ak, aq[kc], s[kn], 0, 0, 0);
            }
        __builtin_amdgcn_s_setprio(0);

        // exp2 (Q pre-scaled) + rowsum + pack P as a full mfma32 B-operand:
        // B k-order = quad*8+j: j 0..3 -> kn0 keys quad*4+j, j 4..7 -> kn1
        // (matches the permuted-VT key order of the va read below).
        u32x4 pbf;
#pragma unroll
        for (int kn = 0; kn < 2; ++kn) {
            float p0 = EXP2(s[kn][0]);
            float p1 = EXP2(s[kn][1]);
            float p2 = EXP2(s[kn][2]);
            float p3 = EXP2(s[kn][3]);
            rs += (p0 + p1) + (p2 + p3);
            pbf[kn * 2 + 0] = pack2(p0, p1);
            pbf[kn * 2 + 1] = pack2(p2, p3);
        }

        // PV: one b128 V read + ONE mfma32 per nj
        __builtin_amdgcn_s_setprio(1);
#pragma unroll
        for (int nj = 0; nj < 4; ++nj) {
            int d = nj * 16 + l16;
            bf16x8 va = *(const bf16x8*)(Vs + d * 32 + quad * 8);
            o[nj] = __builtin_amdgcn_mfma_f32_16x16x32_bf16(
                va, __builtin_bit_cast(bf16x8, pbf), o[nj], 0, 0, 0);
        }
        __builtin_amdgcn_s_setprio(0);

        __syncthreads();              // drains t+1 DMA (hidden) + orders buffer reuse
    }

    // rowsum reduce across quads (keys) and write O^T
    rs += __shfl_xor(rs, 16, 64);
    rs += __shfl_xor(rs, 32, 64);
    const float inv = 1.0f / rs;
    const int q = q0 + w * 16 + l16;
#pragma unroll
    for (int nj = 0; nj < 4; ++nj)
#pragma unroll
        for (int r = 0; r < 4; ++r) {
            int d = nj * 16 + quad * 4 + r;
            dd.ctxT[(size_t)(h * 64 + d) * Nq + q] = f32_bf16(o[nj][r] * inv);
        }
}

// ---------------------------------------------------------------------------
// launch — [convert_all] -> [gemm1] -> [attn] -> [memset d_out] -> [gemm2].
// memset is stream-ordered after attn (d_out's Q/X scratch dead by then) and
// provides the zero-initialized accumulator for gemm2's split-K atomics.
// ---------------------------------------------------------------------------
extern "C" void kernel_launch(void* const* d_in, const int* in_sizes, int n_in,
                              void* d_out, int out_size, void* d_ws, size_t ws_size,
                              hipStream_t stream) {
    u16* ws = (u16*)d_ws;
    u16* A = ws + 64;
    const size_t M1 = 1024ull * 1024;
    const float QSC = 0.125f * 1.44269504089f;   // 1/sqrt(dk) * log2(e)

    u16* W8   = A;              // [0,8M)  : 8 weightsT; [0,3M) later ctx1
    u16* Kd1  = A + 8 * M1;     // [8M,10M) : X@WK natural
    u16* VT   = A + 10 * M1;    // [10M,12M): VT[16][64][2048] (permuted keys)
    u16* K1d  = A + 12 * M1;    // [12M,15M): X1@WK1 natural
    u16* VT1  = A + 15 * M1;    // [15M,18M): VT1[16][64][3072] (permuted keys)
    u16* ctx2 = A + 18 * M1;    // [18M,20M)

    u16* outw = (u16*)d_out;
    u16* Q1s  = outw;           // [0,3M)  X1@WQ1 (bf16 scratch in d_out)
    u16* Qs   = outw + 3 * M1;  // [3M,5M) X@WQ
    u16* Xb   = outw + 5 * M1;  // [5M,7M)  X as bf16
    u16* X1b  = outw + 7 * M1;  // [7M,10M) X1 as bf16

    u16* ctx1 = W8;
    u16* WfcT = W8 + 6 * M1;

    XJob xj0 = {d_in[0], Xb,  2048 * 1024};
    XJob xj1 = {d_in[1], X1b, 3072 * 1024};
    WBatch8 wb;
    for (int i = 0; i < 8; ++i) { wb.j[i].in = d_in[2 + i]; wb.j[i].out = W8 + (size_t)i * M1; }
    convert_all<<<dim3(256, 10), dim3(256), 0, stream>>>(xj0, xj1, wb);

    GemmBatch6 gp;
    gp.j[0] = (GemmJob){Xb,  W8,          Qs,  2048, 0, 0, 0,    QSC};
    gp.j[1] = (GemmJob){Xb,  W8 + M1,     Kd1, 2048, 0, 0, 0,    1.0f};
    gp.j[2] = (GemmJob){Xb,  W8 + 2 * M1, VT,  2048, 0, 0, 2048, 1.0f};
    gp.j[3] = (GemmJob){X1b, W8 + 3 * M1, Q1s, 3072, 0, 0, 0,    QSC};
    gp.j[4] = (GemmJob){X1b, W8 + 4 * M1, K1d, 3072, 0, 0, 0,    1.0f};
    gp.j[5] = (GemmJob){X1b, W8 + 5 * M1, VT1, 3072, 0, 0, 3072, 1.0f};
    gp.flagSrc = (const u16*)d_in[0];
    gp.mode = 1;
    gemm_bt<<<dim3(960), dim3(256), 0, stream>>>(gp);   // flat, LPT, bid%8==m%8

    // dir2 (96-iter blocks) first — longest-processing-time-first
    AttnDir a0 = {Qs,  K1d, VT1, ctx2, 2048, 3072, 512};
    AttnDir a1 = {Q1s, Kd1, VT,  ctx1, 3072, 2048, 768};
    attn_k<<<dim3(1280), dim3(256), 0, stream>>>(a0, a1);

    // zero the split-K accumulator (exactly the 5*M1-element output region)
    hipMemsetAsync(d_out, 0, 5 * M1 * sizeof(float), stream);

    GemmBatch6 gf;
    gf.j[0] = (GemmJob){ctx1, WfcT,      d_out, 3072, 1, 0,               0, 1.0f};
    gf.j[1] = (GemmJob){ctx2, WfcT + M1, d_out, 2048, 1, 3 * 1024 * 1024, 0, 1.0f};
    gf.j[2] = gf.j[0]; gf.j[3] = gf.j[0]; gf.j[4] = gf.j[0]; gf.j[5] = gf.j[0];
    gf.flagSrc = (const u16*)d_in[0];
    gf.mode = 2;
    gemm_bt<<<dim3(640), dim3(256), 0, stream>>>(gf);   // split-K x2
}

// Round 7
// 246.163 us; speedup vs baseline: 1.1454x; 1.1454x over previous
//
#include <hip/hip_runtime.h>
#include <stdint.h>

typedef unsigned short u16;
typedef unsigned int u32;
typedef u16   u16x4  __attribute__((ext_vector_type(4)));
typedef u16   u16x8  __attribute__((ext_vector_type(8)));
typedef __bf16 bf16x8 __attribute__((ext_vector_type(8)));
typedef float f32x4  __attribute__((ext_vector_type(4)));
typedef u32   u32x2  __attribute__((ext_vector_type(2)));
typedef u32   u32x4  __attribute__((ext_vector_type(4)));

typedef __attribute__((address_space(3))) u16 lds_u16;
typedef __attribute__((address_space(1))) const u16 glb_u16;

static __device__ __forceinline__ u16 f32_bf16(float f) {
    uint32_t u = __builtin_bit_cast(uint32_t, f);
    u += 0x7fffu + ((u >> 16) & 1u);          // round-to-nearest-even
    return (u16)(u >> 16);
}
// fast pair-pack: round-half-up + byte-perm (ties-only diff vs RNE)
static __device__ __forceinline__ u32 pack2(float a, float b) {
#if __has_builtin(__builtin_amdgcn_perm)
    u32 ua = __builtin_bit_cast(u32, a) + 0x8000u;
    u32 ub = __builtin_bit_cast(u32, b) + 0x8000u;
    return __builtin_amdgcn_perm(ub, ua, 0x07060302u);   // {ua.hi, ub.hi}
#else
    return (u32)f32_bf16(a) | ((u32)f32_bf16(b) << 16);
#endif
}
#if __has_builtin(__builtin_amdgcn_exp2f)
#define EXP2(x) __builtin_amdgcn_exp2f(x)
#else
#define EXP2(x) __expf((x) * 0.69314718056f)
#endif
static __device__ __forceinline__ u16x8 cvt8(f32x4 a, f32x4 b) {
    u16x8 v;
#pragma unroll
    for (int e = 0; e < 4; ++e) { v[e] = f32_bf16(a[e]); v[4 + e] = f32_bf16(b[e]); }
    return v;
}

// inline dtype-flag (verified R5-R13 semantics): count exps >= 0xC2 in the
// first 1024 u16 of X; >32 -> fp32 inputs AND fp32 output. Deterministic and
// identical in every block -> safe to compute per-block (no detect dispatch).
static __device__ __forceinline__ bool flag_reduce(const u16* __restrict__ X0,
                                                   int* cnt /*>=256 ints LDS*/) {
    const int t = threadIdx.x;
    int c = 0;
#pragma unroll
    for (int i = 0; i < 4; ++i) {
        u16 v = X0[t + 256 * i];
        int e = (v >> 7) & 0xFF;
        c += (e >= 0xC2) ? 1 : 0;
    }
    cnt[t] = c;
    __syncthreads();
    for (int s = 128; s > 0; s >>= 1) {
        if (t < s) cnt[t] += cnt[t + s];
        __syncthreads();
    }
    bool f = cnt[0] > 32;
    __syncthreads();
    return f;
}

// ---------------------------------------------------------------------------
// 0. Merged convert: grid (256, 10). y<2 -> X jobs (bf16 convert / copy),
//    y>=2 -> weight convert+transpose job y-2. Flag computed inline.
// ---------------------------------------------------------------------------
struct XJob { const void* in; u16* out; int n; };
struct WJob { const void* in; u16* out; };
struct WBatch8 { WJob j[8]; };

__global__ __launch_bounds__(256) void convert_all(XJob j0, XJob j1, WBatch8 args) {
    __shared__ int cnt[256];
    __shared__ u16 tile[64][72];
    const bool f32in = flag_reduce((const u16*)j0.in, cnt);
    const int t = threadIdx.x;

    if (blockIdx.y < 2) {
        const XJob job = (blockIdx.y == 0) ? j0 : j1;
        const int stride = gridDim.x * 256 * 8;
        for (int i = ((int)blockIdx.x * 256 + t) * 8; i < job.n; i += stride) {
            u16x8 v;
            if (f32in) {
                const float* p = (const float*)job.in + i;
                v = cvt8(*(const f32x4*)p, *(const f32x4*)(p + 4));
            } else {
                v = *(const u16x8*)((const u16*)job.in + i);
            }
            *(u16x8*)(job.out + i) = v;
        }
        return;
    }

    const int wj = blockIdx.y - 2;
    const void* in = args.j[wj].in;
    u16*       out = args.j[wj].out;
    const int r0 = ((int)blockIdx.x >> 4) * 64, c0 = ((int)blockIdx.x & 15) * 64;
    const int lr = t >> 3, lc = (t & 7) * 8;
#pragma unroll
    for (int pass = 0; pass < 2; ++pass) {
        int r = lr + pass * 32;
        u16x8 v;
        if (f32in) {
            const float* p = (const float*)in + (size_t)(r0 + r) * 1024 + c0 + lc;
            v = cvt8(*(const f32x4*)p, *(const f32x4*)(p + 4));
        } else {
            v = *(const u16x8*)((const u16*)in + (size_t)(r0 + r) * 1024 + c0 + lc);
        }
#pragma unroll
        for (int e = 0; e < 8; ++e) tile[r][lc + e] = v[e];
    }
    __syncthreads();
#pragma unroll
    for (int pass = 0; pass < 2; ++pass) {
        int n = lr + pass * 32;
        u16x8 v;
#pragma unroll
        for (int e = 0; e < 8; ++e) v[e] = tile[lc + e][n];
        *(u16x8*)(out + (size_t)(c0 + n) * 1024 + r0 + lc) = v;
    }
}

// ---------------------------------------------------------------------------
// 2. MFMA GEMM (pre-GEMMs), BK=64, global_load_lds staging. Flat 1-D grid,
//    LPT order, bid%8 == m-tile%8 (XCD L2 locality). Jobs 3,4,5 [M=3072]
//    first, then 0,1,2 [M=2048]; 960 blocks, 128x128 tiles.
//    VT epilogue: permuted key order (R13).
// ---------------------------------------------------------------------------
struct GemmJob  { const u16* A; const u16* Bt; void* C; int M; int cF32able; int cOffElems; int vtNk; float cScale; };
struct GemmBatch6 { GemmJob j[6]; const u16* flagSrc; int mode; };

__global__ __launch_bounds__(256) void gemm_bt(GemmBatch6 b) {
    const int K = 1024, N = 1024;
    int jz, m_t, n_t;
    {
        int bid = blockIdx.x;
        if (bid < 576) { jz = 3 + bid / 192; int r = bid % 192; m_t = r % 24; n_t = r / 24; }
        else { int b2 = bid - 576; jz = b2 / 128; int r = b2 % 128; m_t = r % 16; n_t = r / 16; }
    }
    const GemmJob job = b.j[jz];
    const int m0 = m_t * 128, n0 = n_t * 128;
    if (m0 >= job.M) return;

    __shared__ u16 As[128 * 64];
    __shared__ u16 Bs[128 * 64];

    const int tid  = threadIdx.x;
    const int lane = tid & 63, wave = tid >> 6;
    const int quad = lane >> 4, l16 = lane & 15;
    const int wrow = wave >> 1, wcol = wave & 1;

    f32x4 acc[4][4];
#pragma unroll
    for (int i = 0; i < 4; ++i)
#pragma unroll
        for (int j = 0; j < 4; ++j) acc[i][j] = (f32x4){0.f, 0.f, 0.f, 0.f};

    for (int k0 = 0; k0 < K; k0 += 64) {
        __syncthreads();
#pragma unroll
        for (int i = 0; i < 4; ++i) {
            int id = tid + 256 * i;
            int row = id >> 3, slot = id & 7;
            int src = (slot ^ (row & 7)) * 8;
            __builtin_amdgcn_global_load_lds(
                (glb_u16*)(job.A + (size_t)(m0 + row) * K + k0 + src),
                (lds_u16*)(As + (size_t)id * 8), 16, 0, 0);
            __builtin_amdgcn_global_load_lds(
                (glb_u16*)(job.Bt + (size_t)(n0 + row) * K + k0 + src),
                (lds_u16*)(Bs + (size_t)id * 8), 16, 0, 0);
        }
        __syncthreads();

#pragma unroll
        for (int kc2 = 0; kc2 < 2; ++kc2) {
            bf16x8 af[4], bfb[4];
#pragma unroll
            for (int i = 0; i < 4; ++i) {
                int r  = wrow * 64 + i * 16 + l16;
                af[i]  = *(const bf16x8*)(As + r * 64 + (((kc2 * 4 + quad) ^ (r & 7)) * 8));
                int rn = wcol * 64 + i * 16 + l16;
                bfb[i] = *(const bf16x8*)(Bs + rn * 64 + (((kc2 * 4 + quad) ^ (rn & 7)) * 8));
            }
#pragma unroll
            for (int i = 0; i < 4; ++i)
#pragma unroll
                for (int j = 0; j < 4; ++j)
                    acc[i][j] = __builtin_amdgcn_mfma_f32_16x16x32_bf16(af[i], bfb[j], acc[i][j], 0, 0, 0);
        }
    }

    if (job.vtNk > 0) {
        u16* VT = (u16*)job.C;
        const int Nk2 = job.vtNk;
#pragma unroll
        for (int i = 0; i < 4; ++i)
#pragma unroll
            for (int j = 0; j < 4; ++j) {
                int n   = n0 + wcol * 64 + j * 16 + l16;
                int hh  = n >> 6, dd = n & 63;
                int key = m0 + wrow * 64 + i * 16 + quad * 4;
                int bq  = key & 31;
                int kp  = (key & ~31) | (((bq >> 2) & 3) * 8 + (bq >> 4) * 4);  // permuted
                u16x4 vv;
#pragma unroll
                for (int r = 0; r < 4; ++r) vv[r] = f32_bf16(acc[i][j][r]);
                *(u16x4*)(VT + (size_t)hh * 64 * Nk2 + (size_t)dd * Nk2 + kp) = vv;
            }
    } else {
        u16* C = (u16*)job.C + job.cOffElems;
        const float cs = job.cScale;
#pragma unroll
        for (int i = 0; i < 4; ++i)
#pragma unroll
            for (int j = 0; j < 4; ++j)
#pragma unroll
                for (int r = 0; r < 4; ++r) {
                    int gr = m0 + wrow * 64 + i * 16 + quad * 4 + r;
                    int gc = n0 + wcol * 64 + j * 16 + l16;
                    C[(size_t)gr * N + gc] = f32_bf16(acc[i][j][r] * cs);
                }
    }
}

// ---------------------------------------------------------------------------
// 2b. Final GEMM: 64x128 tiles -> 640 blocks (2.5/CU, 10 waves/CU) vs the
//     old 128x128 (320 blocks, 1.25/CU = occupancy-starved m102-"320 TF"
//     regime). Same staging scheme (rows still 64 k -> identical XOR-8
//     swizzle / ds_read formulas), A=64 rows / B=128 rows, LDS 24 KB.
//     job0 (ctx1, M=3072): 384 blocks; job1 (ctx2, M=2048): 256 blocks.
// ---------------------------------------------------------------------------
__global__ __launch_bounds__(256) void gemm_fin(GemmBatch6 b) {
    const int K = 1024, N = 1024;
    int jz, m_t, n_t;
    {
        int bid = blockIdx.x;
        if (bid < 384) { jz = 0; m_t = bid % 48; n_t = bid / 48; }
        else { int b2 = bid - 384; jz = 1; m_t = b2 % 32; n_t = b2 / 32; }
    }
    const GemmJob job = b.j[jz];
    const int m0 = m_t * 64, n0 = n_t * 128;

    __shared__ u16 As[64 * 64];     // 8 KB
    __shared__ u16 Bs[128 * 64];    // 16 KB

    bool cF = false;
    if (job.cF32able) cF = flag_reduce(b.flagSrc, (int*)As);  // As reused pre-staging

    const int tid  = threadIdx.x;
    const int lane = tid & 63, wave = tid >> 6;   // wave = n-quarter (0..3)
    const int quad = lane >> 4, l16 = lane & 15;

    f32x4 acc[4][2];
#pragma unroll
    for (int i = 0; i < 4; ++i)
#pragma unroll
        for (int j = 0; j < 2; ++j) acc[i][j] = (f32x4){0.f, 0.f, 0.f, 0.f};

    for (int k0 = 0; k0 < K; k0 += 64) {
        __syncthreads();
        // A tile: 64 rows x 64 k = 8 KB -> 2 chunks/thread
#pragma unroll
        for (int i = 0; i < 2; ++i) {
            int id = tid + 256 * i;
            int row = id >> 3, slot = id & 7;
            int src = (slot ^ (row & 7)) * 8;
            __builtin_amdgcn_global_load_lds(
                (glb_u16*)(job.A + (size_t)(m0 + row) * K + k0 + src),
                (lds_u16*)(As + (size_t)id * 8), 16, 0, 0);
        }
        // B tile: 128 rows x 64 k = 16 KB -> 4 chunks/thread
#pragma unroll
        for (int i = 0; i < 4; ++i) {
            int id = tid + 256 * i;
            int row = id >> 3, slot = id & 7;
            int src = (slot ^ (row & 7)) * 8;
            __builtin_amdgcn_global_load_lds(
                (glb_u16*)(job.Bt + (size_t)(n0 + row) * K + k0 + src),
                (lds_u16*)(Bs + (size_t)id * 8), 16, 0, 0);
        }
        __syncthreads();

#pragma unroll
        for (int kc2 = 0; kc2 < 2; ++kc2) {
            bf16x8 af[4], bfb[2];
#pragma unroll
            for (int i = 0; i < 4; ++i) {
                int r  = i * 16 + l16;
                af[i]  = *(const bf16x8*)(As + r * 64 + (((kc2 * 4 + quad) ^ (r & 7)) * 8));
            }
#pragma unroll
            for (int j = 0; j < 2; ++j) {
                int rn = wave * 32 + j * 16 + l16;
                bfb[j] = *(const bf16x8*)(Bs + rn * 64 + (((kc2 * 4 + quad) ^ (rn & 7)) * 8));
            }
#pragma unroll
            for (int i = 0; i < 4; ++i)
#pragma unroll
                for (int j = 0; j < 2; ++j)
                    acc[i][j] = __builtin_amdgcn_mfma_f32_16x16x32_bf16(af[i], bfb[j], acc[i][j], 0, 0, 0);
        }
    }

    if (cF) {
        float* C = (float*)job.C + job.cOffElems;
#pragma unroll
        for (int i = 0; i < 4; ++i)
#pragma unroll
            for (int j = 0; j < 2; ++j)
#pragma unroll
                for (int r = 0; r < 4; ++r) {
                    int gr = m0 + i * 16 + quad * 4 + r;
                    int gc = n0 + wave * 32 + j * 16 + l16;
                    C[(size_t)gr * N + gc] = acc[i][j][r];
                }
    } else {
        u16* C = (u16*)job.C + job.cOffElems;
        const float cs = job.cScale;
#pragma unroll
        for (int i = 0; i < 4; ++i)
#pragma unroll
            for (int j = 0; j < 2; ++j)
#pragma unroll
                for (int r = 0; r < 4; ++r) {
                    int gr = m0 + i * 16 + quad * 4 + r;
                    int gc = n0 + wave * 32 + j * 16 + l16;
                    C[(size_t)gr * N + gc] = f32_bf16(acc[i][j][r] * cs);
                }
    }
}

// ---------------------------------------------------------------------------
// 3. Fused MFMA attention v10 (UNCHANGED — at its LDS-port roofline ~70us):
//    flat wave partition + true 2-phase pipeline. 4 waves each own 16 q-rows;
//    ONE shared K-tile + V-tile (32 keys) per iter, double-buffered (16 KB).
//    Each iter: issue DMA for tile t+1 FIRST, compute tile t, one barrier.
//    (setprio tested R6: null — barrier-locked waves, m190 regime.)
// ---------------------------------------------------------------------------
struct AttnDir { const u16* Q; const u16* K; const u16* VT; u16* ctxT; int Nq; int Nk; int nBlk; };

__global__ __launch_bounds__(256, 8) void attn_k(AttnDir d0, AttnDir d1) {
    const int D = 1024;
    int b = blockIdx.x;
    const AttnDir dd = (b < d0.nBlk) ? d0 : d1;
    if (blockIdx.x >= (unsigned)d0.nBlk) b -= d0.nBlk;
    const int h  = b & 15;
    const int q0 = (b >> 4) * 64;
    const int Nq = dd.Nq, Nk = dd.Nk;
    const u16* __restrict__ Qp  = dd.Q;
    const u16* __restrict__ Kp  = dd.K;
    const u16* __restrict__ VTp = dd.VT;

    const int tid  = threadIdx.x;
    const int lane = tid & 63, w = tid >> 6;
    const int quad = lane >> 4, l16 = lane & 15;

    __shared__ u16 smem[2][4096];     // [buf][K 2048 u16 | V 2048 u16] = 16 KB

    // Q fragments (B operands), pre-scaled by QSC at GEMM time
    bf16x8 aq[2];
#pragma unroll
    for (int kc = 0; kc < 2; ++kc) {
        int q = q0 + w * 16 + l16;
        aq[kc] = *(const bf16x8*)(Qp + (size_t)q * D + h * 64 + kc * 32 + quad * 8);
    }

    f32x4 o[4];                       // O^T accumulators [nj]
#pragma unroll
    for (int nj = 0; nj < 4; ++nj) o[nj] = (f32x4){0.f, 0.f, 0.f, 0.f};
    float rs = 0.f;                   // per-lane partial row-sum (q = l16)

    // staging sources: each thread DMAs one 16B K chunk + one 16B V chunk
    const int krow = tid >> 3;
    const int ksrc = ((tid & 7) ^ (krow & 7)) * 8;      // pre-swizzled global src
    const u16* kg = Kp + (size_t)krow * D + h * 64 + ksrc;
    const u16* vg = VTp + (size_t)h * 64 * Nk + (size_t)(tid >> 2) * Nk + (tid & 3) * 8;

    const int nt = Nk >> 5;
    // prologue: stage tile 0 -> buf 0
    __builtin_amdgcn_global_load_lds((glb_u16*)kg, (lds_u16*)(&smem[0][0] + tid * 8), 16, 0, 0);
    __builtin_amdgcn_global_load_lds((glb_u16*)vg, (lds_u16*)(&smem[0][2048] + tid * 8), 16, 0, 0);
    kg += (size_t)32 * D; vg += 32;
    __syncthreads();

    for (int t = 0; t < nt; ++t) {
        const u16* Ks = &smem[t & 1][0];
        const u16* Vs = Ks + 2048;
        if (t + 1 < nt) {             // issue next-tile DMA BEFORE compute
            u16* dst = &smem[(t + 1) & 1][0];
            __builtin_amdgcn_global_load_lds((glb_u16*)kg, (lds_u16*)(dst + tid * 8), 16, 0, 0);
            __builtin_amdgcn_global_load_lds((glb_u16*)vg, (lds_u16*)(dst + 2048 + tid * 8), 16, 0, 0);
            kg += (size_t)32 * D; vg += 32;
        }

        // S^T = K Q^T   (A = K fragment, B = Q fragment)
        f32x4 s[2];
#pragma unroll
        for (int kn = 0; kn < 2; ++kn) s[kn] = (f32x4){0.f, 0.f, 0.f, 0.f};
#pragma unroll
        for (int kn = 0; kn < 2; ++kn)
#pragma unroll
            for (int kc = 0; kc < 2; ++kc) {
                int keyr = kn * 16 + l16;
                int phys = ((kc * 4 + quad) ^ (keyr & 7)) * 8;
                bf16x8 ak = *(const bf16x8*)(Ks + keyr * 64 + phys);
                s[kn] = __builtin_amdgcn_mfma_f32_16x16x32_bf16(ak, aq[kc], s[kn], 0, 0, 0);
            }

        // exp2 (Q pre-scaled) + rowsum + pack P as a full mfma32 B-operand:
        // B k-order = quad*8+j: j 0..3 -> kn0 keys quad*4+j, j 4..7 -> kn1
        // (matches the permuted-VT key order of the va read below).
        u32x4 pbf;
#pragma unroll
        for (int kn = 0; kn < 2; ++kn) {
            float p0 = EXP2(s[kn][0]);
            float p1 = EXP2(s[kn][1]);
            float p2 = EXP2(s[kn][2]);
            float p3 = EXP2(s[kn][3]);
            rs += (p0 + p1) + (p2 + p3);
            pbf[kn * 2 + 0] = pack2(p0, p1);
            pbf[kn * 2 + 1] = pack2(p2, p3);
        }

        // PV: one b128 V read + ONE mfma32 per nj
#pragma unroll
        for (int nj = 0; nj < 4; ++nj) {
            int d = nj * 16 + l16;
            bf16x8 va = *(const bf16x8*)(Vs + d * 32 + quad * 8);
            o[nj] = __builtin_amdgcn_mfma_f32_16x16x32_bf16(
                va, __builtin_bit_cast(bf16x8, pbf), o[nj], 0, 0, 0);
        }

        __syncthreads();              // drains t+1 DMA (hidden) + orders buffer reuse
    }

    // rowsum reduce across quads (keys) and write O^T
    rs += __shfl_xor(rs, 16, 64);
    rs += __shfl_xor(rs, 32, 64);
    const float inv = 1.0f / rs;
    const int q = q0 + w * 16 + l16;
#pragma unroll
    for (int nj = 0; nj < 4; ++nj)
#pragma unroll
        for (int r = 0; r < 4; ++r) {
            int d = nj * 16 + quad * 4 + r;
            dd.ctxT[(size_t)(h * 64 + d) * Nq + q] = f32_bf16(o[nj][r] * inv);
        }
}

// ---------------------------------------------------------------------------
// launch — 4 dispatches: [convert_all] -> [gemm_bt pre] -> [attn] ->
// [gemm_fin]. No memset / split-K (R6 post-mortem: atomics cost > saving).
// ---------------------------------------------------------------------------
extern "C" void kernel_launch(void* const* d_in, const int* in_sizes, int n_in,
                              void* d_out, int out_size, void* d_ws, size_t ws_size,
                              hipStream_t stream) {
    u16* ws = (u16*)d_ws;
    u16* A = ws + 64;
    const size_t M1 = 1024ull * 1024;
    const float QSC = 0.125f * 1.44269504089f;   // 1/sqrt(dk) * log2(e)

    u16* W8   = A;              // [0,8M)  : 8 weightsT; [0,3M) later ctx1
    u16* Kd1  = A + 8 * M1;     // [8M,10M) : X@WK natural
    u16* VT   = A + 10 * M1;    // [10M,12M): VT[16][64][2048] (permuted keys)
    u16* K1d  = A + 12 * M1;    // [12M,15M): X1@WK1 natural
    u16* VT1  = A + 15 * M1;    // [15M,18M): VT1[16][64][3072] (permuted keys)
    u16* ctx2 = A + 18 * M1;    // [18M,20M)

    u16* outw = (u16*)d_out;
    u16* Q1s  = outw;           // [0,3M)  X1@WQ1 (bf16 scratch in d_out)
    u16* Qs   = outw + 3 * M1;  // [3M,5M) X@WQ
    u16* Xb   = outw + 5 * M1;  // [5M,7M)  X as bf16
    u16* X1b  = outw + 7 * M1;  // [7M,10M) X1 as bf16

    u16* ctx1 = W8;
    u16* WfcT = W8 + 6 * M1;

    XJob xj0 = {d_in[0], Xb,  2048 * 1024};
    XJob xj1 = {d_in[1], X1b, 3072 * 1024};
    WBatch8 wb;
    for (int i = 0; i < 8; ++i) { wb.j[i].in = d_in[2 + i]; wb.j[i].out = W8 + (size_t)i * M1; }
    convert_all<<<dim3(256, 10), dim3(256), 0, stream>>>(xj0, xj1, wb);

    GemmBatch6 gp;
    gp.j[0] = (GemmJob){Xb,  W8,          Qs,  2048, 0, 0, 0,    QSC};
    gp.j[1] = (GemmJob){Xb,  W8 + M1,     Kd1, 2048, 0, 0, 0,    1.0f};
    gp.j[2] = (GemmJob){Xb,  W8 + 2 * M1, VT,  2048, 0, 0, 2048, 1.0f};
    gp.j[3] = (GemmJob){X1b, W8 + 3 * M1, Q1s, 3072, 0, 0, 0,    QSC};
    gp.j[4] = (GemmJob){X1b, W8 + 4 * M1, K1d, 3072, 0, 0, 0,    1.0f};
    gp.j[5] = (GemmJob){X1b, W8 + 5 * M1, VT1, 3072, 0, 0, 3072, 1.0f};
    gp.flagSrc = (const u16*)d_in[0];
    gp.mode = 1;
    gemm_bt<<<dim3(960), dim3(256), 0, stream>>>(gp);   // flat, LPT, bid%8==m%8

    // dir2 (96-iter blocks) first — longest-processing-time-first
    AttnDir a0 = {Qs,  K1d, VT1, ctx2, 2048, 3072, 512};
    AttnDir a1 = {Q1s, Kd1, VT,  ctx1, 3072, 2048, 768};
    attn_k<<<dim3(1280), dim3(256), 0, stream>>>(a0, a1);

    GemmBatch6 gf;
    gf.j[0] = (GemmJob){ctx1, WfcT,      d_out, 3072, 1, 0,               0, 1.0f};
    gf.j[1] = (GemmJob){ctx2, WfcT + M1, d_out, 2048, 1, 3 * 1024 * 1024, 0, 1.0f};
    gf.j[2] = gf.j[0]; gf.j[3] = gf.j[0]; gf.j[4] = gf.j[0]; gf.j[5] = gf.j[0];
    gf.flagSrc = (const u16*)d_in[0];
    gf.mode = 2;
    gemm_fin<<<dim3(640), dim3(256), 0, stream>>>(gf);  // 64x128 tiles, 2.5/CU
}